// Round 13
// baseline (231.003 us; speedup 1.0000x reference)
//
#include <hip/hip_runtime.h>
#include <math.h>

typedef __bf16 bf16x8 __attribute__((ext_vector_type(8)));
typedef float  f32x4  __attribute__((ext_vector_type(4)));
typedef float  f32x16 __attribute__((ext_vector_type(16)));

#define MFMA16(a, b, c) __builtin_amdgcn_mfma_f32_16x16x32_bf16((a), (b), (c), 0, 0, 0)
#define MFMA32(a, b, c) __builtin_amdgcn_mfma_f32_32x32x16_bf16((a), (b), (c), 0, 0, 0)

__device__ __forceinline__ unsigned short f2bf(float f) {
    unsigned int u = __float_as_uint(f);
    u += 0x7fffu + ((u >> 16) & 1u);
    return (unsigned short)(u >> 16);
}

// async global->LDS DMA, 16 B per lane. LDS dest must be wave-uniform base +
// lane*16 (all call sites use lds + tid*8 ushorts).
__device__ __forceinline__ void gll16(const unsigned short* g, unsigned short* l) {
    __builtin_amdgcn_global_load_lds(
        (const __attribute__((address_space(1))) unsigned int*)g,
        (__attribute__((address_space(3))) unsigned int*)l, 16, 0, 0);
}

// ---------------------------------------------------------------------------
// Stage 0: fp32 -> bf16 conversion of h and the 4 weight matrices.
// wq is pre-scaled by 0.125*log2(e) so QK^T emerges in exp2 domain.
// ---------------------------------------------------------------------------
__global__ __launch_bounds__(256) void convert_kernel(
    const float* __restrict__ h, const float* __restrict__ wq,
    const float* __restrict__ wk, const float* __restrict__ wv,
    const float* __restrict__ wo,
    unsigned short* __restrict__ hb, unsigned short* __restrict__ wb)
{
    const int NH4 = 1572864;
    const int NW4 = 147456;
    int i4 = blockIdx.x * 256 + threadIdx.x;
    const float4* src;
    unsigned short* dst;
    int off;
    float sc = 1.0f;
    if (i4 < NH4) {
        src = (const float4*)h; dst = hb; off = i4;
    } else {
        int j = i4 - NH4;
        int w = j / NW4;
        off = j - w * NW4;
        const float* s = (w == 0) ? wq : (w == 1) ? wk : (w == 2) ? wv : wo;
        if (w == 0) sc = 0.18033688011112042f;   // 0.125 * log2(e)
        src = (const float4*)s;
        dst = wb + w * 589824;
    }
    float4 v = src[off];
    ushort4 o;
    o.x = f2bf(v.x * sc); o.y = f2bf(v.y * sc);
    o.z = f2bf(v.z * sc); o.w = f2bf(v.w * sc);
    ((ushort4*)dst)[off] = o;
}

// ---------------------------------------------------------------------------
// Stage 1/4: C = A @ B^T on mfma_f32_32x32x16 (R21). R22: gemm1 widened to
// BM=256 x BN=128 with 512 threads / 8 waves (4M x 2N). Per-wave geometry is
// IDENTICAL to the R21-verified kernel (64x64 output, 8 MFMA32 + 8
// ds_read_b128 per K-iter, same fragment layout, same f(r)=(r&3)^((r>>2)&3)
// LDS involution, same epilogue); only wm/wn, staging (3 gll16/thread/stage,
// vmcnt(3)) and grid decomposition change. Why: 1152 blocks @3/CU was 1.5
// generations (75% packing) and each 128x128 block re-read its A-panel with
// only 128 rows of reuse; 576 blocks @2/CU is 1.125 generations (89%) with
// 2x the A reuse per B-byte. Ring (R15) + XCD-chunked full-column swizzle
// (R18) unchanged. gemm2 keeps BM=128 @256 threads.
// ---------------------------------------------------------------------------
template <typename OutT, int BM>
__global__ __launch_bounds__(BM == 256 ? 512 : 256) void gemm_bt(
    const unsigned short* __restrict__ A,
    const unsigned short* __restrict__ Bm,
    OutT* __restrict__ C)
{
    constexpr int K = 768, N = 768;
    __shared__ unsigned short As[3][BM * 32];
    __shared__ unsigned short Bs[3][128 * 32];

    // flat grid, XCD-chunked bijective swizzle (gridDim.x % 8 == 0).
    // lid decomposition: column tile (nx,z) fastest -> consecutive lids
    // share one A-panel; then bm.
    const int nwg  = gridDim.x;
    const int orig = blockIdx.x;
    const int lid  = (orig & 7) * (nwg >> 3) + (orig >> 3);
    const int ncol = (nwg * BM) >> 13;       // 18 (gemm1) or 6 (gemm2)
    const int cix  = lid % ncol;
    const int bm   = (lid / ncol) * BM;
    const int nx   = cix % 6;
    const int bz   = cix / 6;
    const int bn   = nx * 128;

    const unsigned short* Bz = Bm + (size_t)bz * N * K;
    OutT* Cz = C + (size_t)bz * 8192 * N;

    const int tid  = threadIdx.x;
    const int wave = tid >> 6, lane = tid & 63;
    int wm, wn;
    if constexpr (BM == 256) { wm = (wave & 3) * 64; wn = (wave >> 2) * 64; }
    else                     { wm = (wave & 1) * 64; wn = (wave >> 1) * 64; }
    const int c31  = lane & 31, h = lane >> 5;

    // staging: row = tid>>2, phys chunk p=(tid&3) fetches GLOBAL chunk
    // p ^ f(row), f(r) = (r&3)^((r>>2)&3).
    const int sr  = tid >> 2;                // 0..127 (512t) or 0..63 (256t)
    const int sp8 = ((tid & 3) ^ (sr & 3) ^ ((sr >> 2) & 3)) * 8;
    // read-side: row ≡ c31 mod 32-alignment -> f(row) = swr.
    const int swr = (c31 & 3) ^ ((c31 >> 2) & 3);

    auto stage = [&](int k0, int bi) {
        if constexpr (BM == 256) {
            gll16(A  + (size_t)(bm + sr) * K       + k0 + sp8, As[bi] + tid * 8);
            gll16(A  + (size_t)(bm + 128 + sr) * K + k0 + sp8, As[bi] + 4096 + tid * 8);
            gll16(Bz + (size_t)(bn + sr) * K       + k0 + sp8, Bs[bi] + tid * 8);
        } else {
            gll16(A  + (size_t)(bm + sr) * K      + k0 + sp8, As[bi] + tid * 8);
            gll16(A  + (size_t)(bm + 64 + sr) * K + k0 + sp8, As[bi] + 2048 + tid * 8);
            gll16(Bz + (size_t)(bn + sr) * K      + k0 + sp8, Bs[bi] + tid * 8);
            gll16(Bz + (size_t)(bn + 64 + sr) * K + k0 + sp8, Bs[bi] + 2048 + tid * 8);
        }
    };

    f32x16 acc[2][2] = {};                   // [mi][ni] 32x32 tiles

    // prologue prefetch: K-tiles 0 and 1
    stage(0, 0);
    stage(32, 1);

    int cur = 0;                             // ring index = i % 3
    for (int i = 0; i < 24; i++) {
        // Fused wait+barrier (two-sided fence, R12 lesson). Tile i's DMAs
        // retired per-wave; the 2 newer stages' DMAs stay in flight.
        if (i < 23) {
            if constexpr (BM == 256)
                asm volatile("s_waitcnt vmcnt(3)\n\ts_barrier" ::: "memory");
            else
                asm volatile("s_waitcnt vmcnt(4)\n\ts_barrier" ::: "memory");
        } else {
            asm volatile("s_waitcnt vmcnt(0)\n\ts_barrier" ::: "memory");
        }
        __builtin_amdgcn_sched_barrier(0);

        if (i < 22) {
            int nb = cur + 2; if (nb >= 3) nb -= 3;
            stage((i + 2) * 32, nb);         // overwrites buffer read at i-1
        }

        // fragments: af[mi][c] = A row (wm+mi*32+c31), k-slice (2c+h);
        // bf[ni][c] likewise from B. 8 ds_read_b128 total.
        bf16x8 af[2][2], bfv[2][2];
        #pragma unroll
        for (int mi = 0; mi < 2; mi++)
            #pragma unroll
            for (int c = 0; c < 2; c++) {
                int ch = (2 * c + h) ^ swr;
                af[mi][c]  = *(const bf16x8*)(As[cur] + (wm + mi * 32 + c31) * 32 + ch * 8);
                bfv[mi][c] = *(const bf16x8*)(Bs[cur] + (wn + mi * 32 + c31) * 32 + ch * 8);
            }
        #pragma unroll
        for (int mi = 0; mi < 2; mi++)
            #pragma unroll
            for (int ni = 0; ni < 2; ni++)
                #pragma unroll
                for (int c = 0; c < 2; c++)
                    acc[mi][ni] = MFMA32(af[mi][c], bfv[ni][c], acc[mi][ni]);

        cur = (cur == 2) ? 0 : cur + 1;
    }

    // C-write: acc[mi][ni][reg] -> C[bm+wm+mi*32+rowfn][bn+wn+ni*32+c31],
    // rowfn = (reg&3)+8*(reg>>2)+4*h (verified 32x32 C/D mapping).
    #pragma unroll
    for (int mi = 0; mi < 2; mi++)
        #pragma unroll
        for (int ni = 0; ni < 2; ni++)
            #pragma unroll
            for (int reg = 0; reg < 16; reg++) {
                int rowfn = (reg & 3) + 8 * (reg >> 2) + 4 * h;
                size_t idx = (size_t)(bm + wm + mi * 32 + rowfn) * N
                           + (bn + wn + ni * 32 + c31);
                if constexpr (sizeof(OutT) == 2) Cz[idx] = f2bf(acc[mi][ni][reg]);
                else                             Cz[idx] = acc[mi][ni][reg];
            }
}

// ---------------------------------------------------------------------------
// Stage 2: transpose V per head (head VIEW of the raw reshape):
// [B][24576][64] -> vt[B*12][64][2048].
// ---------------------------------------------------------------------------
__global__ __launch_bounds__(256) void vtrans_kernel(
    const unsigned short* __restrict__ Vg,
    unsigned short* __restrict__ vt)
{
    constexpr int LDT = 72;
    __shared__ unsigned short Ts[64 * LDT];
    const int b = blockIdx.z, hh = blockIdx.y, kp0 = blockIdx.x * 64;
    const int tid = threadIdx.x;
    const size_t boff = (size_t)b * (24576 * 64);
    const int rowV0 = hh * 2048 + kp0;

    #pragma unroll
    for (int rep = 0; rep < 2; rep++) {
        int idx = rep * 256 + tid;
        int r = idx >> 3, dp = (idx & 7) * 8;
        uint4 v = *(const uint4*)(Vg + boff + (size_t)(rowV0 + r) * 64 + dp);
        unsigned short tmp[8];
        *(uint4*)tmp = v;
        #pragma unroll
        for (int i = 0; i < 8; i++) Ts[(dp + i) * LDT + r] = tmp[i];
    }
    __syncthreads();
    unsigned short* vtb = vt + ((size_t)(b * 12 + hh)) * 64 * 2048;
    #pragma unroll
    for (int rep = 0; rep < 2; rep++) {
        int idx = rep * 256 + tid;
        int d = idx >> 3, kp = (idx & 7) * 8;
        uint4 v = *(const uint4*)(Ts + d * LDT + kp);
        *(uint4*)(vtb + (size_t)d * 2048 + kp0 + kp) = v;
    }
}

// ---------------------------------------------------------------------------
// Stage 3: flash attention — R9 structure verbatim (best measured: 77.2 us).
//   - 2-tile ILP iteration, 6-buffer K/V ring, fused s_waitcnt vmcnt(4)
//     s_barrier (R12 lesson), prefetch distance 2, never drains mid-loop.
//   - R14 fine swizzles (bank-conflict 0), T5 setprio, in-register P via
//     cvt_pk+permlane, l via ones-MFMA, XCD-chunked grid (FETCH 18.5 MB).
// ---------------------------------------------------------------------------
__global__ __launch_bounds__(256) void attn_kernel(
    const unsigned short* __restrict__ Qg,
    const unsigned short* __restrict__ Kg,
    const unsigned short* __restrict__ vt,   // [B*12][64][2048]
    const int* __restrict__ mask,            // [B][2048]
    unsigned short* __restrict__ Og)         // [B][24576][64]
{
    __shared__ unsigned short Ks[6 * 2048];  // 6 x [32 kpos][64 d] ring
    __shared__ unsigned short Vs[6 * 2048];  // 6 x [64 d][32 kpos] ring
    __shared__ unsigned long long msh[32];   // mask bitmap; read as u32[64]

    // XCD-chunked flat grid: 768 blocks, 96 per XCD chunk.
    const int orig = blockIdx.x;
    const int lid  = (orig & 7) * 96 + (orig >> 3);
    const int qt   = lid & 15;
    const int bh   = lid >> 4;               // 0..47
    const int hh   = bh % 12;
    const int b    = bh / 12;

    const int tid  = threadIdx.x;
    const int wave = tid >> 6, lane = tid & 63;
    const int c31  = lane & 31, h = lane >> 5;
    const size_t boff = (size_t)b * (24576 * 64);
    const int rowQ0 = hh * 2048 + qt * 128;
    const int rowK0 = hh * 2048;
    const unsigned short* vtg = vt + ((size_t)(b * 12 + hh)) * 64 * 2048;
    // read-side swizzles (must equal the stage-side f(row) involutions)
    const int swk = (c31 & 7) ^ (c31 >> 3);          // K: f(r)=(r&7)^((r>>3)&3)
    const int swv = (c31 & 3) ^ ((c31 >> 2) & 3);    // V: f(r)=(r&3)^((r>>2)&3)

    // K staging: 32 rows x 64 d; row = tid>>3, chunk(8 of 16B) ^= f(row)
    const int srowK = tid >> 3;
    const int schK  = ((tid & 7) ^ (srowK & 7) ^ ((srowK >> 3) & 3)) * 8;
    // V staging: 64 rows x 32 k; row = tid>>2, chunk(4 of 16B) ^= f(row)
    const int srowV = tid >> 2;
    const int schV  = ((tid & 3) ^ (srowV & 3) ^ ((srowV >> 2) & 3)) * 8;

    auto stageKV = [&](int kt, int bi) {
        gll16(Kg  + boff + (size_t)(rowK0 + kt * 32 + srowK) * 64 + schK,
              Ks + bi * 2048 + tid * 8);
        gll16(vtg + (size_t)srowV * 2048 + kt * 32 + schV,
              Vs + bi * 2048 + tid * 8);
    };

    // Q tile: direct global -> registers. qf[c] holds k-slice c*16+8h+j for
    // q-row wave*32+c31, i.e. 16B chunk (2c+h) of the row.
    bf16x8 qf[4];
    {
        const unsigned short* qrow =
            Qg + boff + (size_t)(rowQ0 + wave * 32 + c31) * 64;
        #pragma unroll
        for (int c = 0; c < 4; c++)
            qf[c] = *(const bf16x8*)(qrow + (2 * c + h) * 8);
    }

    // build mask bitmap: thread t covers k-positions [t*8, t*8+8)
    {
        const int4 a = *(const int4*)(mask + b * 2048 + tid * 8);
        const int4 c = *(const int4*)(mask + b * 2048 + tid * 8 + 4);
        unsigned char byte =
            (a.x != 0 ? 1u : 0u)       | (a.y != 0 ? 2u : 0u) |
            (a.z != 0 ? 4u : 0u)       | (a.w != 0 ? 8u : 0u) |
            (c.x != 0 ? 16u : 0u)      | (c.y != 0 ? 32u : 0u) |
            (c.z != 0 ? 64u : 0u)      | (c.w != 0 ? 128u : 0u);
        ((unsigned char*)msh)[tid] = byte;
    }
    // publish msh; vmcnt == 0 entering the loop
    __syncthreads();

    // prologue prefetch: tiles 0..3 -> 8 outstanding DMAs per wave
    stageKV(0, 0);
    stageKV(1, 1);
    stageKV(2, 2);
    stageKV(3, 3);

    f32x16 acc[2] = {};                      // O: row=q-row fn(reg,h), col=d=nt*32+c31
    f32x16 acc_l  = {};                      // row-sum of P (ones-column MFMA)
    bf16x8 onesf;
    #pragma unroll
    for (int i = 0; i < 8; i++) onesf[i] = (__bf16)1.0f;

    int cur = 0;                             // ring index = (2j) % 6
    for (int j = 0; j < 32; j++) {
        // Fused wait+barrier, two-sided compiler memory fence (R12 lesson).
        // Tiles 2j,2j+1's 4 DMAs retired; tiles 2j+2,2j+3's 4 in flight.
        if (j < 31) asm volatile("s_waitcnt vmcnt(4)\n\ts_barrier" ::: "memory");
        else        asm volatile("s_waitcnt vmcnt(0)\n\ts_barrier" ::: "memory");
        __builtin_amdgcn_sched_barrier(0);

        if (j < 30) {
            int nb0 = cur + 4; if (nb0 >= 6) nb0 -= 6;
            int nb1 = cur + 5; if (nb1 >= 6) nb1 -= 6;
            stageKV(2 * j + 4, nb0);         // bufs last read at iter j-1
            stageKV(2 * j + 5, nb1);
        }

        const int c1 = (cur == 5) ? 0 : cur + 1;
        const unsigned int am0 = ((const unsigned int*)msh)[2 * j];
        const unsigned int am1 = ((const unsigned int*)msh)[2 * j + 1];
        const unsigned short* Kc0 = Ks + cur * 2048;
        const unsigned short* Vc0 = Vs + cur * 2048;
        const unsigned short* Kc1 = Ks + c1 * 2048;
        const unsigned short* Vc1 = Vs + c1 * 2048;
        const bool full = (am0 & am1) == 0xFFFFFFFFu;

        // --- tile a = 2j: QK^T -> softmax -> packed P ---
        unsigned int a01[4], a23[4];
        {
            f32x16 z2 = {};
            __builtin_amdgcn_s_setprio(1);
            #pragma unroll
            for (int c = 0; c < 4; c++) {
                int ch = (2 * c + h) ^ swk;
                bf16x8 kf = *(const bf16x8*)(Kc0 + c31 * 64 + ch * 8);
                z2 = MFMA32(kf, qf[c], z2);
            }
            __builtin_amdgcn_s_setprio(0);
            if (full) {
                #pragma unroll
                for (int s = 0; s < 4; s++) {
                    float e0 = __builtin_amdgcn_exp2f(z2[4*s+0]);
                    float e1 = __builtin_amdgcn_exp2f(z2[4*s+1]);
                    float e2 = __builtin_amdgcn_exp2f(z2[4*s+2]);
                    float e3 = __builtin_amdgcn_exp2f(z2[4*s+3]);
                    asm("v_cvt_pk_bf16_f32 %0, %1, %2"
                        : "=v"(a01[s]) : "v"(e0), "v"(e1));
                    asm("v_cvt_pk_bf16_f32 %0, %1, %2"
                        : "=v"(a23[s]) : "v"(e2), "v"(e3));
                }
            } else {
                #pragma unroll
                for (int s = 0; s < 4; s++) {
                    unsigned int nib = (am0 >> (8 * s + 4 * h)) & 0xFu;
                    float e0 = __builtin_amdgcn_exp2f(z2[4*s+0]);
                    float e1 = __builtin_amdgcn_exp2f(z2[4*s+1]);
                    float e2 = __builtin_amdgcn_exp2f(z2[4*s+2]);
                    float e3 = __builtin_amdgcn_exp2f(z2[4*s+3]);
                    e0 = (nib & 1u) ? e0 : 0.f;
                    e1 = (nib & 2u) ? e1 : 0.f;
                    e2 = (nib & 4u) ? e2 : 0.f;
                    e3 = (nib & 8u) ? e3 : 0.f;
                    asm("v_cvt_pk_bf16_f32 %0, %1, %2"
                        : "=v"(a01[s]) : "v"(e0), "v"(e1));
                    asm("v_cvt_pk_bf16_f32 %0, %1, %2"
                        : "=v"(a23[s]) : "v"(e2), "v"(e3));
                }
            }
        }

        // --- tile b = 2j+1: QK^T -> softmax -> packed P ---
        unsigned int b01[4], b23[4];
        {
            f32x16 z2 = {};
            __builtin_amdgcn_s_setprio(1);
            #pragma unroll
            for (int c = 0; c < 4; c++) {
                int ch = (2 * c + h) ^ swk;
                bf16x8 kf = *(const bf16x8*)(Kc1 + c31 * 64 + ch * 8);
                z2 = MFMA32(kf, qf[c], z2);
            }
            __builtin_amdgcn_s_setprio(0);
            if (full) {
                #pragma unroll
                for (int s = 0; s < 4; s++) {
                    float e0 = __builtin_amdgcn_exp2f(z2[4*s+0]);
                    float e1 = __builtin_amdgcn_exp2f(z2[4*s+1]);
                    float e2 = __builtin_amdgcn_exp2f(z2[4*s+2]);
                    float e3 = __builtin_amdgcn_exp2f(z2[4*s+3]);
                    asm("v_cvt_pk_bf16_f32 %0, %1, %2"
                        : "=v"(b01[s]) : "v"(e0), "v"(e1));
                    asm("v_cvt_pk_bf16_f32 %0, %1, %2"
                        : "=v"(b23[s]) : "v"(e2), "v"(e3));
                }
            } else {
                #pragma unroll
                for (int s = 0; s < 4; s++) {
                    unsigned int nib = (am1 >> (8 * s + 4 * h)) & 0xFu;
                    float e0 = __builtin_amdgcn_exp2f(z2[4*s+0]);
                    float e1 = __builtin_amdgcn_exp2f(z2[4*s+1]);
                    float e2 = __builtin_amdgcn_exp2f(z2[4*s+2]);
                    float e3 = __builtin_amdgcn_exp2f(z2[4*s+3]);
                    e0 = (nib & 1u) ? e0 : 0.f;
                    e1 = (nib & 2u) ? e1 : 0.f;
                    e2 = (nib & 4u) ? e2 : 0.f;
                    e3 = (nib & 8u) ? e3 : 0.f;
                    asm("v_cvt_pk_bf16_f32 %0, %1, %2"
                        : "=v"(b01[s]) : "v"(e0), "v"(e1));
                    asm("v_cvt_pk_bf16_f32 %0, %1, %2"
                        : "=v"(b23[s]) : "v"(e2), "v"(e3));
                }
            }
        }

        // --- PV for both tiles (shared acc; chains a/b independent above) ---
        __builtin_amdgcn_s_setprio(1);
        #pragma unroll
        for (int kc = 0; kc < 2; kc++) {
            unsigned int x01 = a01[2 * kc], y01 = a01[2 * kc + 1];
            unsigned int x23 = a23[2 * kc], y23 = a23[2 * kc + 1];
            asm("v_permlane32_swap_b32 %0, %1" : "+v"(x01), "+v"(y01));
            asm("v_permlane32_swap_b32 %0, %1" : "+v"(x23), "+v"(y23));
            uint4 pfu;
            pfu.x = x01; pfu.y = x23; pfu.z = y01; pfu.w = y23;
            bf16x8 pf;
            __builtin_memcpy(&pf, &pfu, 16);
            #pragma unroll
            for (int nt = 0; nt < 2; nt++) {
                int chv = (2 * kc + h) ^ swv;
                bf16x8 vf = *(const bf16x8*)(Vc0 + (nt * 32 + c31) * 32 + chv * 8);
                acc[nt] = MFMA32(pf, vf, acc[nt]);
            }
            acc_l = MFMA32(pf, onesf, acc_l);
        }
        #pragma unroll
        for (int kc = 0; kc < 2; kc++) {
            unsigned int x01 = b01[2 * kc], y01 = b01[2 * kc + 1];
            unsigned int x23 = b23[2 * kc], y23 = b23[2 * kc + 1];
            asm("v_permlane32_swap_b32 %0, %1" : "+v"(x01), "+v"(y01));
            asm("v_permlane32_swap_b32 %0, %1" : "+v"(x23), "+v"(y23));
            uint4 pfu;
            pfu.x = x01; pfu.y = x23; pfu.z = y01; pfu.w = y23;
            bf16x8 pf;
            __builtin_memcpy(&pf, &pfu, 16);
            #pragma unroll
            for (int nt = 0; nt < 2; nt++) {
                int chv = (2 * kc + h) ^ swv;
                bf16x8 vf = *(const bf16x8*)(Vc1 + (nt * 32 + c31) * 32 + chv * 8);
                acc[nt] = MFMA32(pf, vf, acc[nt]);
            }
            acc_l = MFMA32(pf, onesf, acc_l);
        }
        __builtin_amdgcn_s_setprio(0);

        cur = (cur >= 4) ? cur - 4 : cur + 2;    // (cur + 2) % 6
    }

    // epilogue: acc_l[reg] is the full row-sum (same reg->row map as acc) —
    // no cross-lane combine needed.
    #pragma unroll
    for (int reg = 0; reg < 16; reg++) {
        int rowfn = (reg & 3) + 8 * (reg >> 2) + 4 * h;
        float li = __builtin_amdgcn_rcpf(acc_l[reg]);
        int row = rowQ0 + wave * 32 + rowfn;
        #pragma unroll
        for (int nt = 0; nt < 2; nt++)
            Og[boff + (size_t)row * 64 + nt * 32 + c31] = f2bf(acc[nt][reg] * li);
    }
}

// ---------------------------------------------------------------------------
extern "C" void kernel_launch(void* const* d_in, const int* in_sizes, int n_in,
                              void* d_out, int out_size, void* d_ws, size_t ws_size,
                              hipStream_t stream)
{
    const float* h    = (const float*)d_in[0];
    const int*   mask = (const int*)d_in[1];
    const float* wq   = (const float*)d_in[2];
    const float* wk   = (const float*)d_in[3];
    const float* wv   = (const float*)d_in[4];
    const float* wo   = (const float*)d_in[5];

    // ws layout (ushorts): hb (reused as V^T) | wb | qkv | ctx = 67.6 MB
    unsigned short* hb  = (unsigned short*)d_ws;
    unsigned short* wb  = hb + 6291456;
    unsigned short* qkv = wb + 4 * 589824;
    unsigned short* ctx = qkv + (size_t)3 * 6291456;

    convert_kernel<<<8448, 256, 0, stream>>>(h, wq, wk, wv, wo, hb, wb);
    gemm_bt<unsigned short, 256><<<576, 512, 0, stream>>>(hb, wb, qkv);
    // hb dead after gemm1 -> reuse as V^T
    vtrans_kernel<<<dim3(32, 12, 4), 256, 0, stream>>>(
        qkv + (size_t)2 * 6291456, hb);
    attn_kernel<<<768, 256, 0, stream>>>(
        qkv, qkv + 6291456, hb, mask, ctx);
    gemm_bt<float, 128><<<384, 256, 0, stream>>>(
        ctx, wb + (size_t)3 * 589824, (float*)d_out);
}

// Round 14
// 219.138 us; speedup vs baseline: 1.0541x; 1.0541x over previous
//
#include <hip/hip_runtime.h>
#include <math.h>

typedef __bf16 bf16x8 __attribute__((ext_vector_type(8)));
typedef float  f32x4  __attribute__((ext_vector_type(4)));
typedef float  f32x16 __attribute__((ext_vector_type(16)));

#define MFMA16(a, b, c) __builtin_amdgcn_mfma_f32_16x16x32_bf16((a), (b), (c), 0, 0, 0)
#define MFMA32(a, b, c) __builtin_amdgcn_mfma_f32_32x32x16_bf16((a), (b), (c), 0, 0, 0)

__device__ __forceinline__ unsigned short f2bf(float f) {
    unsigned int u = __float_as_uint(f);
    u += 0x7fffu + ((u >> 16) & 1u);
    return (unsigned short)(u >> 16);
}

// async global->LDS DMA, 16 B per lane. LDS dest must be wave-uniform base +
// lane*16 (all call sites use lds + tid*8 ushorts).
__device__ __forceinline__ void gll16(const unsigned short* g, unsigned short* l) {
    __builtin_amdgcn_global_load_lds(
        (const __attribute__((address_space(1))) unsigned int*)g,
        (__attribute__((address_space(3))) unsigned int*)l, 16, 0, 0);
}

// ---------------------------------------------------------------------------
// Stage 0: fp32 -> bf16 conversion of h and the 4 weight matrices.
// wq is pre-scaled by 0.125*log2(e) so QK^T emerges in exp2 domain.
// ---------------------------------------------------------------------------
__global__ __launch_bounds__(256) void convert_kernel(
    const float* __restrict__ h, const float* __restrict__ wq,
    const float* __restrict__ wk, const float* __restrict__ wv,
    const float* __restrict__ wo,
    unsigned short* __restrict__ hb, unsigned short* __restrict__ wb)
{
    const int NH4 = 1572864;
    const int NW4 = 147456;
    int i4 = blockIdx.x * 256 + threadIdx.x;
    const float4* src;
    unsigned short* dst;
    int off;
    float sc = 1.0f;
    if (i4 < NH4) {
        src = (const float4*)h; dst = hb; off = i4;
    } else {
        int j = i4 - NH4;
        int w = j / NW4;
        off = j - w * NW4;
        const float* s = (w == 0) ? wq : (w == 1) ? wk : (w == 2) ? wv : wo;
        if (w == 0) sc = 0.18033688011112042f;   // 0.125 * log2(e)
        src = (const float4*)s;
        dst = wb + w * 589824;
    }
    float4 v = src[off];
    ushort4 o;
    o.x = f2bf(v.x * sc); o.y = f2bf(v.y * sc);
    o.z = f2bf(v.z * sc); o.w = f2bf(v.w * sc);
    ((ushort4*)dst)[off] = o;
}

// ---------------------------------------------------------------------------
// Stage 1/4: C = A @ B^T on mfma_f32_32x32x16 (R21 kernel, measured best at
// 128x128 in R23 after the 256-tile experiment regressed). R23: BN templated
// — gemm2 runs BN=64 (768 blocks = 3/CU uniform, killing the 1.5-blocks/CU
// tail where half the CUs idled for half the kernel); gemm1 keeps 128x128
// (1152 blocks). Per-wave geometry within the verified MFMA32 family:
// BN=128 -> wave 64x64, acc[2][2]; BN=64 -> wave 64x32, acc[2][1]. Same
// fragment layout, same f(r)=(r&3)^((r>>2)&3) LDS involution, same verified
// C/D epilogue mapping. Ring (R15) + XCD-chunked full-column swizzle (R18).
// ---------------------------------------------------------------------------
template <typename OutT, int BN>
__global__ __launch_bounds__(256) void gemm_bt(
    const unsigned short* __restrict__ A,
    const unsigned short* __restrict__ Bm,
    OutT* __restrict__ C)
{
    constexpr int K = 768, N = 768;
    constexpr int NI = BN / 64;              // 2 (gemm1) or 1 (gemm2)
    __shared__ unsigned short As[3][128 * 32];
    __shared__ unsigned short Bs[3][BN * 32];

    // flat grid, XCD-chunked bijective swizzle (gridDim.x % 8 == 0).
    // lid decomposition: column tile fastest -> consecutive lids share one
    // A-panel; then bm. ncol = nwg>>6 (1152->18, 768->12).
    const int nwg  = gridDim.x;
    const int orig = blockIdx.x;
    const int lid  = (orig & 7) * (nwg >> 3) + (orig >> 3);
    const int ncol = nwg >> 6;
    const int cix  = lid % ncol;
    const int bm   = (lid / ncol) * 128;
    int nx, bz;
    if constexpr (BN == 128) { nx = cix % 6; bz = cix / 6; }
    else                     { nx = cix;     bz = 0;       }
    const int bn   = nx * BN;

    const unsigned short* Bz = Bm + (size_t)bz * N * K;
    OutT* Cz = C + (size_t)bz * 8192 * N;

    const int tid  = threadIdx.x;
    const int wave = tid >> 6, lane = tid & 63;
    const int wm   = (wave & 1) * 64;
    const int wn   = (wave >> 1) * (BN / 2); // 64 (BN=128) or 32 (BN=64)
    const int c31  = lane & 31, h = lane >> 5;

    // staging: row = tid>>2, phys chunk p=(tid&3) fetches GLOBAL chunk
    // p ^ f(row), f(r) = (r&3)^((r>>2)&3).
    const int sr  = tid >> 2;
    const int sp8 = ((tid & 3) ^ (sr & 3) ^ ((sr >> 2) & 3)) * 8;
    // read-side: row ≡ c31 mod 32-alignment -> f(row) = swr.
    const int swr = (c31 & 3) ^ ((c31 >> 2) & 3);

    auto stage = [&](int k0, int bi) {
        gll16(A + (size_t)(bm + sr) * K      + k0 + sp8, As[bi] + tid * 8);
        gll16(A + (size_t)(bm + 64 + sr) * K + k0 + sp8, As[bi] + 2048 + tid * 8);
        gll16(Bz + (size_t)(bn + sr) * K     + k0 + sp8, Bs[bi] + tid * 8);
        if constexpr (BN == 128)
            gll16(Bz + (size_t)(bn + 64 + sr) * K + k0 + sp8, Bs[bi] + 2048 + tid * 8);
    };

    f32x16 acc[2][NI] = {};                  // [mi][ni] 32x32 tiles

    // prologue prefetch: K-tiles 0 and 1
    stage(0, 0);
    stage(32, 1);

    int cur = 0;                             // ring index = i % 3
    for (int i = 0; i < 24; i++) {
        // Fused wait+barrier (two-sided fence, R12 lesson). Tile i's DMAs
        // retired per-wave; tile i+1's stay in flight (N = DMAs/stage).
        if (i < 23) {
            if constexpr (BN == 128)
                asm volatile("s_waitcnt vmcnt(4)\n\ts_barrier" ::: "memory");
            else
                asm volatile("s_waitcnt vmcnt(3)\n\ts_barrier" ::: "memory");
        } else {
            asm volatile("s_waitcnt vmcnt(0)\n\ts_barrier" ::: "memory");
        }
        __builtin_amdgcn_sched_barrier(0);

        if (i < 22) {
            int nb = cur + 2; if (nb >= 3) nb -= 3;
            stage((i + 2) * 32, nb);         // overwrites buffer read at i-1
        }

        // fragments: af[mi][c] = A row (wm+mi*32+c31), k-slice (2c+h);
        // bfv[ni][c] = B row (wn+ni*32+c31).
        bf16x8 af[2][2], bfv[NI][2];
        #pragma unroll
        for (int c = 0; c < 2; c++) {
            int ch = (2 * c + h) ^ swr;
            #pragma unroll
            for (int mi = 0; mi < 2; mi++)
                af[mi][c] = *(const bf16x8*)(As[cur] + (wm + mi * 32 + c31) * 32 + ch * 8);
            #pragma unroll
            for (int ni = 0; ni < NI; ni++)
                bfv[ni][c] = *(const bf16x8*)(Bs[cur] + (wn + ni * 32 + c31) * 32 + ch * 8);
        }
        #pragma unroll
        for (int mi = 0; mi < 2; mi++)
            #pragma unroll
            for (int ni = 0; ni < NI; ni++)
                #pragma unroll
                for (int c = 0; c < 2; c++)
                    acc[mi][ni] = MFMA32(af[mi][c], bfv[ni][c], acc[mi][ni]);

        cur = (cur == 2) ? 0 : cur + 1;
    }

    // C-write: acc[mi][ni][reg] -> C[bm+wm+mi*32+rowfn][bn+wn+ni*32+c31],
    // rowfn = (reg&3)+8*(reg>>2)+4*h (verified 32x32 C/D mapping).
    #pragma unroll
    for (int mi = 0; mi < 2; mi++)
        #pragma unroll
        for (int ni = 0; ni < NI; ni++)
            #pragma unroll
            for (int reg = 0; reg < 16; reg++) {
                int rowfn = (reg & 3) + 8 * (reg >> 2) + 4 * h;
                size_t idx = (size_t)(bm + wm + mi * 32 + rowfn) * N
                           + (bn + wn + ni * 32 + c31);
                if constexpr (sizeof(OutT) == 2) Cz[idx] = f2bf(acc[mi][ni][reg]);
                else                             Cz[idx] = acc[mi][ni][reg];
            }
}

// ---------------------------------------------------------------------------
// Stage 2: transpose V per head (head VIEW of the raw reshape):
// [B][24576][64] -> vt[B*12][64][2048].
// ---------------------------------------------------------------------------
__global__ __launch_bounds__(256) void vtrans_kernel(
    const unsigned short* __restrict__ Vg,
    unsigned short* __restrict__ vt)
{
    constexpr int LDT = 72;
    __shared__ unsigned short Ts[64 * LDT];
    const int b = blockIdx.z, hh = blockIdx.y, kp0 = blockIdx.x * 64;
    const int tid = threadIdx.x;
    const size_t boff = (size_t)b * (24576 * 64);
    const int rowV0 = hh * 2048 + kp0;

    #pragma unroll
    for (int rep = 0; rep < 2; rep++) {
        int idx = rep * 256 + tid;
        int r = idx >> 3, dp = (idx & 7) * 8;
        uint4 v = *(const uint4*)(Vg + boff + (size_t)(rowV0 + r) * 64 + dp);
        unsigned short tmp[8];
        *(uint4*)tmp = v;
        #pragma unroll
        for (int i = 0; i < 8; i++) Ts[(dp + i) * LDT + r] = tmp[i];
    }
    __syncthreads();
    unsigned short* vtb = vt + ((size_t)(b * 12 + hh)) * 64 * 2048;
    #pragma unroll
    for (int rep = 0; rep < 2; rep++) {
        int idx = rep * 256 + tid;
        int d = idx >> 3, kp = (idx & 7) * 8;
        uint4 v = *(const uint4*)(Ts + d * LDT + kp);
        *(uint4*)(vtb + (size_t)d * 2048 + kp0 + kp) = v;
    }
}

// ---------------------------------------------------------------------------
// Stage 3: flash attention — R9 structure verbatim (best measured: 77.2 us).
//   - 2-tile ILP iteration, 6-buffer K/V ring, fused s_waitcnt vmcnt(4)
//     s_barrier (R12 lesson), prefetch distance 2, never drains mid-loop.
//   - R14 fine swizzles (bank-conflict 0), T5 setprio, in-register P via
//     cvt_pk+permlane, l via ones-MFMA, XCD-chunked grid (FETCH 18.5 MB).
// ---------------------------------------------------------------------------
__global__ __launch_bounds__(256) void attn_kernel(
    const unsigned short* __restrict__ Qg,
    const unsigned short* __restrict__ Kg,
    const unsigned short* __restrict__ vt,   // [B*12][64][2048]
    const int* __restrict__ mask,            // [B][2048]
    unsigned short* __restrict__ Og)         // [B][24576][64]
{
    __shared__ unsigned short Ks[6 * 2048];  // 6 x [32 kpos][64 d] ring
    __shared__ unsigned short Vs[6 * 2048];  // 6 x [64 d][32 kpos] ring
    __shared__ unsigned long long msh[32];   // mask bitmap; read as u32[64]

    // XCD-chunked flat grid: 768 blocks, 96 per XCD chunk.
    const int orig = blockIdx.x;
    const int lid  = (orig & 7) * 96 + (orig >> 3);
    const int qt   = lid & 15;
    const int bh   = lid >> 4;               // 0..47
    const int hh   = bh % 12;
    const int b    = bh / 12;

    const int tid  = threadIdx.x;
    const int wave = tid >> 6, lane = tid & 63;
    const int c31  = lane & 31, h = lane >> 5;
    const size_t boff = (size_t)b * (24576 * 64);
    const int rowQ0 = hh * 2048 + qt * 128;
    const int rowK0 = hh * 2048;
    const unsigned short* vtg = vt + ((size_t)(b * 12 + hh)) * 64 * 2048;
    // read-side swizzles (must equal the stage-side f(row) involutions)
    const int swk = (c31 & 7) ^ (c31 >> 3);          // K: f(r)=(r&7)^((r>>3)&3)
    const int swv = (c31 & 3) ^ ((c31 >> 2) & 3);    // V: f(r)=(r&3)^((r>>2)&3)

    // K staging: 32 rows x 64 d; row = tid>>3, chunk(8 of 16B) ^= f(row)
    const int srowK = tid >> 3;
    const int schK  = ((tid & 7) ^ (srowK & 7) ^ ((srowK >> 3) & 3)) * 8;
    // V staging: 64 rows x 32 k; row = tid>>2, chunk(4 of 16B) ^= f(row)
    const int srowV = tid >> 2;
    const int schV  = ((tid & 3) ^ (srowV & 3) ^ ((srowV >> 2) & 3)) * 8;

    auto stageKV = [&](int kt, int bi) {
        gll16(Kg  + boff + (size_t)(rowK0 + kt * 32 + srowK) * 64 + schK,
              Ks + bi * 2048 + tid * 8);
        gll16(vtg + (size_t)srowV * 2048 + kt * 32 + schV,
              Vs + bi * 2048 + tid * 8);
    };

    // Q tile: direct global -> registers. qf[c] holds k-slice c*16+8h+j for
    // q-row wave*32+c31, i.e. 16B chunk (2c+h) of the row.
    bf16x8 qf[4];
    {
        const unsigned short* qrow =
            Qg + boff + (size_t)(rowQ0 + wave * 32 + c31) * 64;
        #pragma unroll
        for (int c = 0; c < 4; c++)
            qf[c] = *(const bf16x8*)(qrow + (2 * c + h) * 8);
    }

    // build mask bitmap: thread t covers k-positions [t*8, t*8+8)
    {
        const int4 a = *(const int4*)(mask + b * 2048 + tid * 8);
        const int4 c = *(const int4*)(mask + b * 2048 + tid * 8 + 4);
        unsigned char byte =
            (a.x != 0 ? 1u : 0u)       | (a.y != 0 ? 2u : 0u) |
            (a.z != 0 ? 4u : 0u)       | (a.w != 0 ? 8u : 0u) |
            (c.x != 0 ? 16u : 0u)      | (c.y != 0 ? 32u : 0u) |
            (c.z != 0 ? 64u : 0u)      | (c.w != 0 ? 128u : 0u);
        ((unsigned char*)msh)[tid] = byte;
    }
    // publish msh; vmcnt == 0 entering the loop
    __syncthreads();

    // prologue prefetch: tiles 0..3 -> 8 outstanding DMAs per wave
    stageKV(0, 0);
    stageKV(1, 1);
    stageKV(2, 2);
    stageKV(3, 3);

    f32x16 acc[2] = {};                      // O: row=q-row fn(reg,h), col=d=nt*32+c31
    f32x16 acc_l  = {};                      // row-sum of P (ones-column MFMA)
    bf16x8 onesf;
    #pragma unroll
    for (int i = 0; i < 8; i++) onesf[i] = (__bf16)1.0f;

    int cur = 0;                             // ring index = (2j) % 6
    for (int j = 0; j < 32; j++) {
        // Fused wait+barrier, two-sided compiler memory fence (R12 lesson).
        // Tiles 2j,2j+1's 4 DMAs retired; tiles 2j+2,2j+3's 4 in flight.
        if (j < 31) asm volatile("s_waitcnt vmcnt(4)\n\ts_barrier" ::: "memory");
        else        asm volatile("s_waitcnt vmcnt(0)\n\ts_barrier" ::: "memory");
        __builtin_amdgcn_sched_barrier(0);

        if (j < 30) {
            int nb0 = cur + 4; if (nb0 >= 6) nb0 -= 6;
            int nb1 = cur + 5; if (nb1 >= 6) nb1 -= 6;
            stageKV(2 * j + 4, nb0);         // bufs last read at iter j-1
            stageKV(2 * j + 5, nb1);
        }

        const int c1 = (cur == 5) ? 0 : cur + 1;
        const unsigned int am0 = ((const unsigned int*)msh)[2 * j];
        const unsigned int am1 = ((const unsigned int*)msh)[2 * j + 1];
        const unsigned short* Kc0 = Ks + cur * 2048;
        const unsigned short* Vc0 = Vs + cur * 2048;
        const unsigned short* Kc1 = Ks + c1 * 2048;
        const unsigned short* Vc1 = Vs + c1 * 2048;
        const bool full = (am0 & am1) == 0xFFFFFFFFu;

        // --- tile a = 2j: QK^T -> softmax -> packed P ---
        unsigned int a01[4], a23[4];
        {
            f32x16 z2 = {};
            __builtin_amdgcn_s_setprio(1);
            #pragma unroll
            for (int c = 0; c < 4; c++) {
                int ch = (2 * c + h) ^ swk;
                bf16x8 kf = *(const bf16x8*)(Kc0 + c31 * 64 + ch * 8);
                z2 = MFMA32(kf, qf[c], z2);
            }
            __builtin_amdgcn_s_setprio(0);
            if (full) {
                #pragma unroll
                for (int s = 0; s < 4; s++) {
                    float e0 = __builtin_amdgcn_exp2f(z2[4*s+0]);
                    float e1 = __builtin_amdgcn_exp2f(z2[4*s+1]);
                    float e2 = __builtin_amdgcn_exp2f(z2[4*s+2]);
                    float e3 = __builtin_amdgcn_exp2f(z2[4*s+3]);
                    asm("v_cvt_pk_bf16_f32 %0, %1, %2"
                        : "=v"(a01[s]) : "v"(e0), "v"(e1));
                    asm("v_cvt_pk_bf16_f32 %0, %1, %2"
                        : "=v"(a23[s]) : "v"(e2), "v"(e3));
                }
            } else {
                #pragma unroll
                for (int s = 0; s < 4; s++) {
                    unsigned int nib = (am0 >> (8 * s + 4 * h)) & 0xFu;
                    float e0 = __builtin_amdgcn_exp2f(z2[4*s+0]);
                    float e1 = __builtin_amdgcn_exp2f(z2[4*s+1]);
                    float e2 = __builtin_amdgcn_exp2f(z2[4*s+2]);
                    float e3 = __builtin_amdgcn_exp2f(z2[4*s+3]);
                    e0 = (nib & 1u) ? e0 : 0.f;
                    e1 = (nib & 2u) ? e1 : 0.f;
                    e2 = (nib & 4u) ? e2 : 0.f;
                    e3 = (nib & 8u) ? e3 : 0.f;
                    asm("v_cvt_pk_bf16_f32 %0, %1, %2"
                        : "=v"(a01[s]) : "v"(e0), "v"(e1));
                    asm("v_cvt_pk_bf16_f32 %0, %1, %2"
                        : "=v"(a23[s]) : "v"(e2), "v"(e3));
                }
            }
        }

        // --- tile b = 2j+1: QK^T -> softmax -> packed P ---
        unsigned int b01[4], b23[4];
        {
            f32x16 z2 = {};
            __builtin_amdgcn_s_setprio(1);
            #pragma unroll
            for (int c = 0; c < 4; c++) {
                int ch = (2 * c + h) ^ swk;
                bf16x8 kf = *(const bf16x8*)(Kc1 + c31 * 64 + ch * 8);
                z2 = MFMA32(kf, qf[c], z2);
            }
            __builtin_amdgcn_s_setprio(0);
            if (full) {
                #pragma unroll
                for (int s = 0; s < 4; s++) {
                    float e0 = __builtin_amdgcn_exp2f(z2[4*s+0]);
                    float e1 = __builtin_amdgcn_exp2f(z2[4*s+1]);
                    float e2 = __builtin_amdgcn_exp2f(z2[4*s+2]);
                    float e3 = __builtin_amdgcn_exp2f(z2[4*s+3]);
                    asm("v_cvt_pk_bf16_f32 %0, %1, %2"
                        : "=v"(b01[s]) : "v"(e0), "v"(e1));
                    asm("v_cvt_pk_bf16_f32 %0, %1, %2"
                        : "=v"(b23[s]) : "v"(e2), "v"(e3));
                }
            } else {
                #pragma unroll
                for (int s = 0; s < 4; s++) {
                    unsigned int nib = (am1 >> (8 * s + 4 * h)) & 0xFu;
                    float e0 = __builtin_amdgcn_exp2f(z2[4*s+0]);
                    float e1 = __builtin_amdgcn_exp2f(z2[4*s+1]);
                    float e2 = __builtin_amdgcn_exp2f(z2[4*s+2]);
                    float e3 = __builtin_amdgcn_exp2f(z2[4*s+3]);
                    e0 = (nib & 1u) ? e0 : 0.f;
                    e1 = (nib & 2u) ? e1 : 0.f;
                    e2 = (nib & 4u) ? e2 : 0.f;
                    e3 = (nib & 8u) ? e3 : 0.f;
                    asm("v_cvt_pk_bf16_f32 %0, %1, %2"
                        : "=v"(b01[s]) : "v"(e0), "v"(e1));
                    asm("v_cvt_pk_bf16_f32 %0, %1, %2"
                        : "=v"(b23[s]) : "v"(e2), "v"(e3));
                }
            }
        }

        // --- PV for both tiles (shared acc; chains a/b independent above) ---
        __builtin_amdgcn_s_setprio(1);
        #pragma unroll
        for (int kc = 0; kc < 2; kc++) {
            unsigned int x01 = a01[2 * kc], y01 = a01[2 * kc + 1];
            unsigned int x23 = a23[2 * kc], y23 = a23[2 * kc + 1];
            asm("v_permlane32_swap_b32 %0, %1" : "+v"(x01), "+v"(y01));
            asm("v_permlane32_swap_b32 %0, %1" : "+v"(x23), "+v"(y23));
            uint4 pfu;
            pfu.x = x01; pfu.y = x23; pfu.z = y01; pfu.w = y23;
            bf16x8 pf;
            __builtin_memcpy(&pf, &pfu, 16);
            #pragma unroll
            for (int nt = 0; nt < 2; nt++) {
                int chv = (2 * kc + h) ^ swv;
                bf16x8 vf = *(const bf16x8*)(Vc0 + (nt * 32 + c31) * 32 + chv * 8);
                acc[nt] = MFMA32(pf, vf, acc[nt]);
            }
            acc_l = MFMA32(pf, onesf, acc_l);
        }
        #pragma unroll
        for (int kc = 0; kc < 2; kc++) {
            unsigned int x01 = b01[2 * kc], y01 = b01[2 * kc + 1];
            unsigned int x23 = b23[2 * kc], y23 = b23[2 * kc + 1];
            asm("v_permlane32_swap_b32 %0, %1" : "+v"(x01), "+v"(y01));
            asm("v_permlane32_swap_b32 %0, %1" : "+v"(x23), "+v"(y23));
            uint4 pfu;
            pfu.x = x01; pfu.y = x23; pfu.z = y01; pfu.w = y23;
            bf16x8 pf;
            __builtin_memcpy(&pf, &pfu, 16);
            #pragma unroll
            for (int nt = 0; nt < 2; nt++) {
                int chv = (2 * kc + h) ^ swv;
                bf16x8 vf = *(const bf16x8*)(Vc1 + (nt * 32 + c31) * 32 + chv * 8);
                acc[nt] = MFMA32(pf, vf, acc[nt]);
            }
            acc_l = MFMA32(pf, onesf, acc_l);
        }
        __builtin_amdgcn_s_setprio(0);

        cur = (cur >= 4) ? cur - 4 : cur + 2;    // (cur + 2) % 6
    }

    // epilogue: acc_l[reg] is the full row-sum (same reg->row map as acc) —
    // no cross-lane combine needed.
    #pragma unroll
    for (int reg = 0; reg < 16; reg++) {
        int rowfn = (reg & 3) + 8 * (reg >> 2) + 4 * h;
        float li = __builtin_amdgcn_rcpf(acc_l[reg]);
        int row = rowQ0 + wave * 32 + rowfn;
        #pragma unroll
        for (int nt = 0; nt < 2; nt++)
            Og[boff + (size_t)row * 64 + nt * 32 + c31] = f2bf(acc[nt][reg] * li);
    }
}

// ---------------------------------------------------------------------------
extern "C" void kernel_launch(void* const* d_in, const int* in_sizes, int n_in,
                              void* d_out, int out_size, void* d_ws, size_t ws_size,
                              hipStream_t stream)
{
    const float* h    = (const float*)d_in[0];
    const int*   mask = (const int*)d_in[1];
    const float* wq   = (const float*)d_in[2];
    const float* wk   = (const float*)d_in[3];
    const float* wv   = (const float*)d_in[4];
    const float* wo   = (const float*)d_in[5];

    // ws layout (ushorts): hb (reused as V^T) | wb | qkv | ctx = 67.6 MB
    unsigned short* hb  = (unsigned short*)d_ws;
    unsigned short* wb  = hb + 6291456;
    unsigned short* qkv = wb + 4 * 589824;
    unsigned short* ctx = qkv + (size_t)3 * 6291456;

    convert_kernel<<<8448, 256, 0, stream>>>(h, wq, wk, wv, wo, hb, wb);
    gemm_bt<unsigned short, 128><<<1152, 256, 0, stream>>>(hb, wb, qkv);
    // hb dead after gemm1 -> reuse as V^T
    vtrans_kernel<<<dim3(32, 12, 4), 256, 0, stream>>>(
        qkv + (size_t)2 * 6291456, hb);
    attn_kernel<<<768, 256, 0, stream>>>(
        qkv, qkv + 6291456, hb, mask, ctx);
    gemm_bt<float, 64><<<768, 256, 0, stream>>>(
        ctx, wb + (size_t)3 * 589824, (float*)d_out);
}